// Round 10
// baseline (176.575 us; speedup 1.0000x reference)
//
#include <hip/hip_runtime.h>

#define TEMP 5.656854249492380195f   // sqrt(32)
#define EPSG 1e-10f

#define ROWP 516                     // padded row stride (floats)
#define BSTR (8 * ROWP)              // per-b stride in sh (4128 floats)

// ---------- K1: 2 b's/block, LDS-staged hidden, per-lane full-dot ----------
// grid 2048; wave w: qk=w&1, bb=w>>1; lane=(v:8, dg:8). Lane computes
// q[v][dg*4..+3] (or k) for one b over K=512. acc = 4 VGPRs; no butterfly.
// LDS 37 KB -> 4 blocks/CU (16 waves/CU).
__launch_bounds__(256, 2)
__global__ void k1_kernel(const float* __restrict__ hidden,
                          const float* __restrict__ u_var,
                          const float* __restrict__ Wq,
                          const float* __restrict__ bq,
                          const float* __restrict__ Wk,
                          const float* __restrict__ bk,
                          const float* __restrict__ rule_emb,
                          const float* __restrict__ Wk2,
                          const float* __restrict__ bk2,
                          float* __restrict__ k2f,
                          int* __restrict__ cnt,
                          int* __restrict__ selbuf,
                          float* __restrict__ outbuf) {
    const int tid = threadIdx.x;
    const int b0  = blockIdx.x * 2;

    __shared__ float sh[2 * BSTR];      // 2 padded b's (33 KB)
    __shared__ float s_qk[2][2][8][32]; // [b][q/k][v][d] (4 KB)

    // merged K0 (block 0 only): k2 = rule_emb@Wk2 + bk2 ; cnt = 0
    if (blockIdx.x == 0) {
        if (tid < 16) cnt[tid] = 0;
        for (int t = tid; t < 512; t += 256) {
            int r = t >> 5, d = t & 31;
            float acc = bk2[d];
            for (int h = 0; h < 64; ++h)
                acc += rule_emb[r * 64 + h] * Wk2[h * 32 + d];
            k2f[t] = acc;
        }
    }

    // ---- stage 2 b's of hidden into padded LDS ----
    {
        const float4* src = reinterpret_cast<const float4*>(hidden + (size_t)b0 * 4096);
        #pragma unroll
        for (int c = 0; c < 8; ++c) {
            int f   = c * 256 + tid;          // float4 flat idx 0..2047
            int bb  = f >> 10;
            int rem = f & 1023;
            int v   = rem >> 7;
            int cc  = rem & 127;
            reinterpret_cast<float4*>(sh)[bb * (BSTR / 4) + v * (ROWP / 4) + cc] = src[f];
        }
    }
    __syncthreads();

    // ---- projection: lane-owned full dot (x from LDS, w from L2) ----
    {
        const int lane = tid & 63;
        const int w    = tid >> 6;        // wave id
        const int qk   = w & 1;
        const int bb   = w >> 1;          // 0 or 1
        const int v    = lane >> 3;
        const int dg   = lane & 7;

        const float* Wsrc = (qk ? Wk : Wq) + dg * 4;
        const float* xp   = &sh[bb * BSTR + v * ROWP];

        float4 acc = make_float4(0.f, 0.f, 0.f, 0.f);

        #pragma unroll 4
        for (int g = 0; g < 128; ++g) {
            const int h = g * 4;
            const float* wrow = Wsrc + (size_t)h * 32;
            float4 w0 = *reinterpret_cast<const float4*>(wrow);
            float4 w1 = *reinterpret_cast<const float4*>(wrow + 32);
            float4 w2 = *reinterpret_cast<const float4*>(wrow + 64);
            float4 w3 = *reinterpret_cast<const float4*>(wrow + 96);
            float4 x  = *reinterpret_cast<const float4*>(xp + h);
            acc.x += x.x * w0.x + x.y * w1.x + x.z * w2.x + x.w * w3.x;
            acc.y += x.x * w0.y + x.y * w1.y + x.z * w2.y + x.w * w3.y;
            acc.z += x.x * w0.z + x.y * w1.z + x.z * w2.z + x.w * w3.z;
            acc.w += x.x * w0.w + x.y * w1.w + x.z * w2.w + x.w * w3.w;
        }

        const float* bsrc = (qk ? bk : bq) + dg * 4;
        float4 bias4 = *reinterpret_cast<const float4*>(bsrc);
        float4 r;
        r.x = acc.x + bias4.x; r.y = acc.y + bias4.y;
        r.z = acc.z + bias4.z; r.w = acc.w + bias4.w;
        *reinterpret_cast<float4*>(&s_qk[bb][qk][v][dg * 4]) = r;
    }
    __syncthreads();

    // ---- waves 0-1: scores + gumbel + 64-way argmax (wave w -> b0+w) ----
    if (tid < 128) {
        const int w    = tid >> 6;
        const int lane = tid & 63;
        const int b    = b0 + w;
        const int i = lane >> 3, j = lane & 7;
        float s = 0.f;
        #pragma unroll
        for (int d4 = 0; d4 < 8; ++d4) {
            float4 qv = *reinterpret_cast<const float4*>(&s_qk[w][0][i][d4 * 4]);
            float4 kv = *reinterpret_cast<const float4*>(&s_qk[w][1][j][d4 * 4]);
            s += qv.x * kv.x + qv.y * kv.y + qv.z * kv.z + qv.w * kv.w;
        }
        s /= TEMP;
        float u = u_var[(size_t)b * 64 + lane];
        float g = -logf(-logf(u + EPSG) + EPSG);
        float pm = s + g;
        int idx = lane;
        #pragma unroll
        for (int off = 32; off >= 1; off >>= 1) {
            float pv = __shfl_xor(pm, off);
            int   pi = __shfl_xor(idx, off);
            if (pv > pm || (pv == pm && pi < idx)) { pm = pv; idx = pi; }
        }
        if (lane == 0) selbuf[b] = idx;
    }

    // ---- hmean -> outbuf[b][0..511] (scratch; K3 overwrites later) ----
    {
        const int bb   = tid >> 7;        // 0 or 1
        const int l    = tid & 127;
        const int h0   = l * 4;
        const float* base = &sh[bb * BSTR];
        float m[4];
        #pragma unroll
        for (int t = 0; t < 4; ++t) m[t] = 0.f;
        #pragma unroll
        for (int v = 0; v < 8; ++v) {
            float4 a = *reinterpret_cast<const float4*>(base + v * ROWP + h0);
            m[0] += a.x; m[1] += a.y; m[2] += a.z; m[3] += a.w;
        }
        float4 o = make_float4(m[0] * 0.125f, m[1] * 0.125f, m[2] * 0.125f, m[3] * 0.125f);
        *reinterpret_cast<float4*>(outbuf + (size_t)(b0 + bb) * 4096 + h0) = o;
    }
}

// ---------- K2: q2 GEMM + rule gumbel argmax + rule buckets ----------------
__launch_bounds__(256, 4)
__global__ void k2sel_kernel(const float* __restrict__ hidden,
                             const float* __restrict__ u_rule,
                             const float* __restrict__ Wq2,
                             const float* __restrict__ bq2,
                             const float* __restrict__ k2f,
                             const int* __restrict__ selbuf,
                             const float* __restrict__ hmeanbuf,
                             int* __restrict__ cnt,
                             int* __restrict__ list) {
    const int tid = threadIdx.x;
    const int b0 = blockIdx.x * 8;

    __shared__ float  s_k2[512];
    __shared__ float  xt[8][256];
    __shared__ float4 part4[4][8][8];
    __shared__ float  s_q2[8][32];
    __shared__ int    s_sel8[8];

    s_k2[tid]       = k2f[tid];
    s_k2[tid + 256] = k2f[tid + 256];
    if (tid < 8) s_sel8[tid] = selbuf[b0 + tid];
    __syncthreads();

    const int d4 = tid & 7, s = tid >> 3;
    float4 acc[8];
    #pragma unroll
    for (int bb = 0; bb < 8; ++bb) acc[bb] = make_float4(0.f, 0.f, 0.f, 0.f);

    for (int kt = 0; kt < 6; ++kt) {
        float4 w[8];
        #pragma unroll
        for (int j = 0; j < 8; ++j)
            w[j] = *reinterpret_cast<const float4*>(Wq2 + (size_t)(kt * 256 + s * 8 + j) * 32 + d4 * 4);
        #pragma unroll
        for (int bb = 0; bb < 8; ++bb) {
            const int b  = b0 + bb;
            const int sv = s_sel8[bb];
            const float* src;
            if (kt < 2)      src = hidden  + ((size_t)b * 8 + (sv & 7))  * 512 + kt * 256;
            else if (kt < 4) src = hidden  + ((size_t)b * 8 + (sv >> 3)) * 512 + (kt - 2) * 256;
            else             src = hmeanbuf + (size_t)b * 4096 + (kt - 4) * 256;
            xt[bb][tid] = src[tid];
        }
        __syncthreads();
        #pragma unroll
        for (int bb = 0; bb < 8; ++bb) {
            #pragma unroll
            for (int j = 0; j < 8; ++j) {
                float x = xt[bb][s * 8 + j];
                acc[bb].x += x * w[j].x;
                acc[bb].y += x * w[j].y;
                acc[bb].z += x * w[j].z;
                acc[bb].w += x * w[j].w;
            }
        }
        __syncthreads();
    }
    #pragma unroll
    for (int off = 8; off < 64; off <<= 1) {
        #pragma unroll
        for (int bb = 0; bb < 8; ++bb) {
            acc[bb].x += __shfl_xor(acc[bb].x, off);
            acc[bb].y += __shfl_xor(acc[bb].y, off);
            acc[bb].z += __shfl_xor(acc[bb].z, off);
            acc[bb].w += __shfl_xor(acc[bb].w, off);
        }
    }
    if ((s & 7) == 0) {
        #pragma unroll
        for (int bb = 0; bb < 8; ++bb) part4[tid >> 6][bb][d4] = acc[bb];
    }
    __syncthreads();
    {
        const int bb = tid >> 5, col = tid & 31;
        float q2 = bq2[col];
        #pragma unroll
        for (int wv = 0; wv < 4; ++wv) {
            const float* pf = reinterpret_cast<const float*>(&part4[wv][bb][col >> 2]);
            q2 += pf[col & 3];
        }
        s_q2[bb][col] = q2;
    }
    __syncthreads();
    if (tid < 128) {
        const int bb = tid >> 4, r = tid & 15;
        const int b = b0 + bb;
        float sc = 0.f;
        #pragma unroll
        for (int d = 0; d < 32; ++d) sc += s_q2[bb][d] * s_k2[r * 32 + d];
        sc /= TEMP;
        float u = u_rule[(size_t)b * 16 + r];
        float g = -logf(-logf(u + EPSG) + EPSG);
        float pm = sc + g;
        int idx = r;
        #pragma unroll
        for (int off = 8; off >= 1; off >>= 1) {
            float pv = __shfl_xor(pm, off, 16);
            int   pi = __shfl_xor(idx, off, 16);
            if (pv > pm || (pv == pm && pi < idx)) { pm = pv; idx = pi; }
        }
        if (r == 0) {
            int pos = atomicAdd(&cnt[idx], 1);
            list[idx * 4096 + pos] = b;
        }
    }
}

// ---------- K3: rule-bucketed MLP + full output write ----------------------
__launch_bounds__(256, 2)
__global__ void k3_kernel(const float* __restrict__ hidden,
                          const float* __restrict__ W1,
                          const float* __restrict__ W2,
                          const int* __restrict__ selbuf,
                          const int* __restrict__ cnt,
                          const int* __restrict__ list,
                          float* __restrict__ outbuf) {
    const int tid = threadIdx.x;
    const int r   = blockIdx.x & 15;       // rule
    const int c   = blockIdx.x >> 4;       // chunk 0..31

    __shared__ float w1s[16384];           // W1[r] as [row*16+e] (64 KB)
    __shared__ float comb[1024];
    __shared__ float part[4][16];
    __shared__ float s_h1[16];

    #pragma unroll
    for (int i = 0; i < 16; ++i) {
        int idx = i * 1024 + tid * 4;
        *reinterpret_cast<float4*>(&w1s[idx]) =
            *reinterpret_cast<const float4*>(W1 + (size_t)r * 16384 + idx);
    }
    const int n = cnt[r];
    __syncthreads();

    const int e  = tid & 15;
    const int sl = tid >> 4;

    for (int idx = c; idx < n; idx += 32) {
        const int b  = list[r * 4096 + idx];
        const int sv = selbuf[b];
        const int js = sv & 7, cs = sv >> 3;

        {
            const float4* h4 = reinterpret_cast<const float4*>(hidden);
            float4 v;
            if (tid < 128) v = h4[((size_t)b * 8 + js) * 128 + tid];
            else           v = h4[((size_t)b * 8 + cs) * 128 + (tid - 128)];
            *reinterpret_cast<float4*>(&comb[tid * 4]) = v;
        }
        __syncthreads();

        float a = 0.f;
        for (int i = 0; i < 64; ++i) {
            int rr = i * 16 + sl;
            a += comb[rr] * w1s[rr * 16 + e];
        }
        a += __shfl_xor(a, 16);
        a += __shfl_xor(a, 32);
        if ((sl & 3) == 0) part[sl >> 2][e] = a;
        __syncthreads();
        if (tid < 16)
            s_h1[tid] = fmaxf(part[0][tid] + part[1][tid] + part[2][tid] + part[3][tid], 0.f);
        __syncthreads();

        const float* w2 = W2 + (size_t)r * 8192;
        int o0 = tid * 2;
        float a0 = 0.f, a1 = 0.f;
        #pragma unroll
        for (int ee = 0; ee < 16; ++ee) {
            float h1e = s_h1[ee];
            float2 ww = *reinterpret_cast<const float2*>(w2 + ee * 512 + o0);
            a0 += h1e * ww.x;
            a1 += h1e * ww.y;
        }
        float2 nz = make_float2(a0, a1);
        float2 zz = make_float2(0.f, 0.f);
        float2* ob = reinterpret_cast<float2*>(outbuf + (size_t)b * 4096);
        #pragma unroll
        for (int v = 0; v < 8; ++v)
            ob[v * 256 + tid] = (v == js) ? nz : zz;
    }
}

extern "C" void kernel_launch(void* const* d_in, const int* in_sizes, int n_in,
                              void* d_out, int out_size, void* d_ws, size_t ws_size,
                              hipStream_t stream) {
    const float* hidden   = (const float*)d_in[0];
    const float* u_var    = (const float*)d_in[1];
    const float* u_rule   = (const float*)d_in[2];
    const float* Wq       = (const float*)d_in[3];
    const float* bq       = (const float*)d_in[4];
    const float* Wk       = (const float*)d_in[5];
    const float* bk       = (const float*)d_in[6];
    const float* rule_emb = (const float*)d_in[7];
    const float* Wq2      = (const float*)d_in[8];
    const float* bq2      = (const float*)d_in[9];
    const float* Wk2      = (const float*)d_in[10];
    const float* bk2      = (const float*)d_in[11];
    const float* W1       = (const float*)d_in[12];
    const float* W2       = (const float*)d_in[13];

    char* ws = (char*)d_ws;
    float* k2f  = (float*)(ws);              // 512 f32
    int*   cnt  = (int*)(ws + 2048);         // 16 i32
    int*   sel  = (int*)(ws + 4096);         // 4096 i32
    int*   list = (int*)(ws + 20480);        // 16*4096 i32
    float* outf = (float*)d_out;

    hipLaunchKernelGGL(k1_kernel, dim3(2048), dim3(256), 0, stream,
                       hidden, u_var, Wq, bq, Wk, bk,
                       rule_emb, Wk2, bk2, k2f, cnt, sel, outf);
    hipLaunchKernelGGL(k2sel_kernel, dim3(512), dim3(256), 0, stream,
                       hidden, u_rule, Wq2, bq2, k2f, sel, outf, cnt, list);
    hipLaunchKernelGGL(k3_kernel, dim3(512), dim3(256), 0, stream,
                       hidden, W1, W2, sel, cnt, list, outf);
}

// Round 11
// 95.672 us; speedup vs baseline: 1.8456x; 1.8456x over previous
//
#include <hip/hip_runtime.h>

#define TEMP 5.656854249492380195f   // sqrt(32)
#define EPSG 1e-10f

// K1 GEMM geometry: M-tile 64 (8 b x 8 v), N 64 (q|k), K chunk 64, 8 chunks.
#define XSTR 68                      // x-tile row stride (floats), 16B-aligned, bank-spread
#define WSTR 64                      // w-tile row stride

// ---------- K1: canonical LDS GEMM for q/k projection + argmax + hmean -----
// block = 8 b's (grid 512); thread (tm:16, tn:16) owns a 4x4 micro-tile of
// the 64x64 output. Both x and W staged in LDS per K-chunk -> compute phase
// is 8 ds_read_b128 : 64 FMA per k4-step. FP expression identical to all
// passing rounds (same 4-term contraction, k ascending) -> no argmax flips.
__launch_bounds__(256, 2)
__global__ void k1_kernel(const float* __restrict__ hidden,
                          const float* __restrict__ u_var,
                          const float* __restrict__ Wq,
                          const float* __restrict__ bq,
                          const float* __restrict__ Wk,
                          const float* __restrict__ bk,
                          const float* __restrict__ rule_emb,
                          const float* __restrict__ Wk2,
                          const float* __restrict__ bk2,
                          float* __restrict__ k2f,
                          int* __restrict__ cnt,
                          int* __restrict__ selbuf,
                          float* __restrict__ outbuf) {
    const int tid = threadIdx.x;
    const int b0  = blockIdx.x * 8;

    // xt [64][XSTR] (17.4 KB) | wt [64][WSTR] (16 KB) -> 33.8 KB total.
    // Epilogue s_qk [64][XSTR] aliases the xt region.
    __shared__ float4 smem4[(64 * XSTR + 64 * WSTR) / 4];
    float* smem = reinterpret_cast<float*>(smem4);
    float* xt = smem;
    float* wt = smem + 64 * XSTR;

    // merged K0 (block 0 only): k2 = rule_emb@Wk2 + bk2 ; cnt = 0
    if (blockIdx.x == 0) {
        if (tid < 16) cnt[tid] = 0;
        for (int t = tid; t < 512; t += 256) {
            int r = t >> 5, d = t & 31;
            float acc = bk2[d];
            for (int h = 0; h < 64; ++h)
                acc += rule_emb[r * 64 + h] * Wk2[h * 32 + d];
            k2f[t] = acc;
        }
    }

    const int tn = tid & 15;          // output col group (cols tn*4..+3)
    const int tm = tid >> 4;          // output row group (rows tm*4..+3)

    float4 acc0 = make_float4(0.f, 0.f, 0.f, 0.f);
    float4 acc1 = make_float4(0.f, 0.f, 0.f, 0.f);
    float4 acc2 = make_float4(0.f, 0.f, 0.f, 0.f);
    float4 acc3 = make_float4(0.f, 0.f, 0.f, 0.f);

    for (int c = 0; c < 8; ++c) {
        // ---- stage x-chunk and w-chunk into LDS ----
        #pragma unroll
        for (int p = 0; p < 4; ++p) {
            int f   = p * 256 + tid;      // 0..1023
            int row = f >> 4;             // 0..63  (= bb*8+v)
            int c4  = f & 15;
            int bb  = row >> 3, v = row & 7;
            float4 val = *reinterpret_cast<const float4*>(
                hidden + (size_t)(b0 + bb) * 4096 + v * 512 + c * 64 + c4 * 4);
            *reinterpret_cast<float4*>(&xt[row * XSTR + c4 * 4]) = val;
        }
        #pragma unroll
        for (int p = 0; p < 4; ++p) {
            int f  = p * 256 + tid;
            int k  = f >> 4;              // 0..63
            int n4 = f & 15;              // 0..15
            int h  = c * 64 + k;
            const float* src = (n4 < 8) ? (Wq + h * 32 + n4 * 4)
                                        : (Wk + h * 32 + (n4 - 8) * 4);
            *reinterpret_cast<float4*>(&wt[k * WSTR + n4 * 4]) =
                *reinterpret_cast<const float4*>(src);
        }
        __syncthreads();

        // ---- compute: 16 k4-steps, 8 ds_read_b128 : 64 FMA each ----
        #pragma unroll 4
        for (int k4 = 0; k4 < 16; ++k4) {
            float4 x0 = *reinterpret_cast<const float4*>(&xt[(tm * 4 + 0) * XSTR + k4 * 4]);
            float4 x1 = *reinterpret_cast<const float4*>(&xt[(tm * 4 + 1) * XSTR + k4 * 4]);
            float4 x2 = *reinterpret_cast<const float4*>(&xt[(tm * 4 + 2) * XSTR + k4 * 4]);
            float4 x3 = *reinterpret_cast<const float4*>(&xt[(tm * 4 + 3) * XSTR + k4 * 4]);
            float4 w0 = *reinterpret_cast<const float4*>(&wt[(k4 * 4 + 0) * WSTR + tn * 4]);
            float4 w1 = *reinterpret_cast<const float4*>(&wt[(k4 * 4 + 1) * WSTR + tn * 4]);
            float4 w2 = *reinterpret_cast<const float4*>(&wt[(k4 * 4 + 2) * WSTR + tn * 4]);
            float4 w3 = *reinterpret_cast<const float4*>(&wt[(k4 * 4 + 3) * WSTR + tn * 4]);
            acc0.x += x0.x * w0.x + x0.y * w1.x + x0.z * w2.x + x0.w * w3.x;
            acc0.y += x0.x * w0.y + x0.y * w1.y + x0.z * w2.y + x0.w * w3.y;
            acc0.z += x0.x * w0.z + x0.y * w1.z + x0.z * w2.z + x0.w * w3.z;
            acc0.w += x0.x * w0.w + x0.y * w1.w + x0.z * w2.w + x0.w * w3.w;
            acc1.x += x1.x * w0.x + x1.y * w1.x + x1.z * w2.x + x1.w * w3.x;
            acc1.y += x1.x * w0.y + x1.y * w1.y + x1.z * w2.y + x1.w * w3.y;
            acc1.z += x1.x * w0.z + x1.y * w1.z + x1.z * w2.z + x1.w * w3.z;
            acc1.w += x1.x * w0.w + x1.y * w1.w + x1.z * w2.w + x1.w * w3.w;
            acc2.x += x2.x * w0.x + x2.y * w1.x + x2.z * w2.x + x2.w * w3.x;
            acc2.y += x2.x * w0.y + x2.y * w1.y + x2.z * w2.y + x2.w * w3.y;
            acc2.z += x2.x * w0.z + x2.y * w1.z + x2.z * w2.z + x2.w * w3.z;
            acc2.w += x2.x * w0.w + x2.y * w1.w + x2.z * w2.w + x2.w * w3.w;
            acc3.x += x3.x * w0.x + x3.y * w1.x + x3.z * w2.x + x3.w * w3.x;
            acc3.y += x3.x * w0.y + x3.y * w1.y + x3.z * w2.y + x3.w * w3.y;
            acc3.z += x3.x * w0.z + x3.y * w1.z + x3.z * w2.z + x3.w * w3.z;
            acc3.w += x3.x * w0.w + x3.y * w1.w + x3.z * w2.w + x3.w * w3.w;
        }

        // ---- hmean partial for this chunk (reads xt; v ascending) ----
        {
            int bb = tid >> 5, hg = tid & 31;   // 8 b x 32 col-pairs
            float m0 = 0.f, m1 = 0.f;
            #pragma unroll
            for (int v = 0; v < 8; ++v) {
                float2 x2 = *reinterpret_cast<const float2*>(&xt[(bb * 8 + v) * XSTR + hg * 2]);
                m0 += x2.x; m1 += x2.y;
            }
            float2 o; o.x = m0 * 0.125f; o.y = m1 * 0.125f;
            *reinterpret_cast<float2*>(outbuf + (size_t)(b0 + bb) * 4096 + c * 64 + hg * 2) = o;
        }
        __syncthreads();
    }

    // ---- epilogue: bias + write scores to LDS (aliases xt region) ----
    {
        const float* bsrc = (tn < 8) ? (bq + tn * 4) : (bk + (tn - 8) * 4);
        float4 bias4 = *reinterpret_cast<const float4*>(bsrc);
        float4 r0, r1, r2, r3;
        r0.x = acc0.x + bias4.x; r0.y = acc0.y + bias4.y; r0.z = acc0.z + bias4.z; r0.w = acc0.w + bias4.w;
        r1.x = acc1.x + bias4.x; r1.y = acc1.y + bias4.y; r1.z = acc1.z + bias4.z; r1.w = acc1.w + bias4.w;
        r2.x = acc2.x + bias4.x; r2.y = acc2.y + bias4.y; r2.z = acc2.z + bias4.z; r2.w = acc2.w + bias4.w;
        r3.x = acc3.x + bias4.x; r3.y = acc3.y + bias4.y; r3.z = acc3.z + bias4.z; r3.w = acc3.w + bias4.w;
        float* sq = smem;   // s_qk[row][XSTR]: cols 0-31 q, 32-63 k
        *reinterpret_cast<float4*>(&sq[(tm * 4 + 0) * XSTR + tn * 4]) = r0;
        *reinterpret_cast<float4*>(&sq[(tm * 4 + 1) * XSTR + tn * 4]) = r1;
        *reinterpret_cast<float4*>(&sq[(tm * 4 + 2) * XSTR + tn * 4]) = r2;
        *reinterpret_cast<float4*>(&sq[(tm * 4 + 3) * XSTR + tn * 4]) = r3;
    }
    __syncthreads();

    // ---- per-wave 64-lane argmax; wave w handles b0+w and b0+w+4 ----
    {
        const float* sq = smem;
        const int w    = tid >> 6;
        const int lane = tid & 63;
        #pragma unroll
        for (int half = 0; half < 2; ++half) {
            const int bb = w + half * 4;
            const int b  = b0 + bb;
            const int i = lane >> 3, j = lane & 7;
            float s = 0.f;
            #pragma unroll
            for (int d4 = 0; d4 < 8; ++d4) {
                float4 qv = *reinterpret_cast<const float4*>(&sq[(bb * 8 + i) * XSTR + d4 * 4]);
                float4 kv = *reinterpret_cast<const float4*>(&sq[(bb * 8 + j) * XSTR + 32 + d4 * 4]);
                s += qv.x * kv.x + qv.y * kv.y + qv.z * kv.z + qv.w * kv.w;
            }
            s /= TEMP;
            float u = u_var[(size_t)b * 64 + lane];
            float g = -logf(-logf(u + EPSG) + EPSG);
            float pm = s + g;
            int idx = lane;
            #pragma unroll
            for (int off = 32; off >= 1; off >>= 1) {
                float pv = __shfl_xor(pm, off);
                int   pi = __shfl_xor(idx, off);
                if (pv > pm || (pv == pm && pi < idx)) { pm = pv; idx = pi; }
            }
            if (lane == 0) selbuf[b] = idx;
        }
    }
}

// ---------- K2: q2 GEMM + rule gumbel argmax + rule buckets ----------------
__launch_bounds__(256, 4)
__global__ void k2sel_kernel(const float* __restrict__ hidden,
                             const float* __restrict__ u_rule,
                             const float* __restrict__ Wq2,
                             const float* __restrict__ bq2,
                             const float* __restrict__ k2f,
                             const int* __restrict__ selbuf,
                             const float* __restrict__ hmeanbuf,
                             int* __restrict__ cnt,
                             int* __restrict__ list) {
    const int tid = threadIdx.x;
    const int b0 = blockIdx.x * 8;

    __shared__ float  s_k2[512];
    __shared__ float  xt[8][256];
    __shared__ float4 part4[4][8][8];
    __shared__ float  s_q2[8][32];
    __shared__ int    s_sel8[8];

    s_k2[tid]       = k2f[tid];
    s_k2[tid + 256] = k2f[tid + 256];
    if (tid < 8) s_sel8[tid] = selbuf[b0 + tid];
    __syncthreads();

    const int d4 = tid & 7, s = tid >> 3;
    float4 acc[8];
    #pragma unroll
    for (int bb = 0; bb < 8; ++bb) acc[bb] = make_float4(0.f, 0.f, 0.f, 0.f);

    for (int kt = 0; kt < 6; ++kt) {
        float4 w[8];
        #pragma unroll
        for (int j = 0; j < 8; ++j)
            w[j] = *reinterpret_cast<const float4*>(Wq2 + (size_t)(kt * 256 + s * 8 + j) * 32 + d4 * 4);
        #pragma unroll
        for (int bb = 0; bb < 8; ++bb) {
            const int b  = b0 + bb;
            const int sv = s_sel8[bb];
            const float* src;
            if (kt < 2)      src = hidden  + ((size_t)b * 8 + (sv & 7))  * 512 + kt * 256;
            else if (kt < 4) src = hidden  + ((size_t)b * 8 + (sv >> 3)) * 512 + (kt - 2) * 256;
            else             src = hmeanbuf + (size_t)b * 4096 + (kt - 4) * 256;
            xt[bb][tid] = src[tid];
        }
        __syncthreads();
        #pragma unroll
        for (int bb = 0; bb < 8; ++bb) {
            #pragma unroll
            for (int j = 0; j < 8; ++j) {
                float x = xt[bb][s * 8 + j];
                acc[bb].x += x * w[j].x;
                acc[bb].y += x * w[j].y;
                acc[bb].z += x * w[j].z;
                acc[bb].w += x * w[j].w;
            }
        }
        __syncthreads();
    }
    #pragma unroll
    for (int off = 8; off < 64; off <<= 1) {
        #pragma unroll
        for (int bb = 0; bb < 8; ++bb) {
            acc[bb].x += __shfl_xor(acc[bb].x, off);
            acc[bb].y += __shfl_xor(acc[bb].y, off);
            acc[bb].z += __shfl_xor(acc[bb].z, off);
            acc[bb].w += __shfl_xor(acc[bb].w, off);
        }
    }
    if ((s & 7) == 0) {
        #pragma unroll
        for (int bb = 0; bb < 8; ++bb) part4[tid >> 6][bb][d4] = acc[bb];
    }
    __syncthreads();
    {
        const int bb = tid >> 5, col = tid & 31;
        float q2 = bq2[col];
        #pragma unroll
        for (int wv = 0; wv < 4; ++wv) {
            const float* pf = reinterpret_cast<const float*>(&part4[wv][bb][col >> 2]);
            q2 += pf[col & 3];
        }
        s_q2[bb][col] = q2;
    }
    __syncthreads();
    if (tid < 128) {
        const int bb = tid >> 4, r = tid & 15;
        const int b = b0 + bb;
        float sc = 0.f;
        #pragma unroll
        for (int d = 0; d < 32; ++d) sc += s_q2[bb][d] * s_k2[r * 32 + d];
        sc /= TEMP;
        float u = u_rule[(size_t)b * 16 + r];
        float g = -logf(-logf(u + EPSG) + EPSG);
        float pm = sc + g;
        int idx = r;
        #pragma unroll
        for (int off = 8; off >= 1; off >>= 1) {
            float pv = __shfl_xor(pm, off, 16);
            int   pi = __shfl_xor(idx, off, 16);
            if (pv > pm || (pv == pm && pi < idx)) { pm = pv; idx = pi; }
        }
        if (r == 0) {
            int pos = atomicAdd(&cnt[idx], 1);
            list[idx * 4096 + pos] = b;
        }
    }
}

// ---------- K3: rule-bucketed MLP + full output write ----------------------
__launch_bounds__(256, 2)
__global__ void k3_kernel(const float* __restrict__ hidden,
                          const float* __restrict__ W1,
                          const float* __restrict__ W2,
                          const int* __restrict__ selbuf,
                          const int* __restrict__ cnt,
                          const int* __restrict__ list,
                          float* __restrict__ outbuf) {
    const int tid = threadIdx.x;
    const int r   = blockIdx.x & 15;       // rule
    const int c   = blockIdx.x >> 4;       // chunk 0..31

    __shared__ float w1s[16384];           // W1[r] as [row*16+e] (64 KB)
    __shared__ float comb[1024];
    __shared__ float part[4][16];
    __shared__ float s_h1[16];

    #pragma unroll
    for (int i = 0; i < 16; ++i) {
        int idx = i * 1024 + tid * 4;
        *reinterpret_cast<float4*>(&w1s[idx]) =
            *reinterpret_cast<const float4*>(W1 + (size_t)r * 16384 + idx);
    }
    const int n = cnt[r];
    __syncthreads();

    const int e  = tid & 15;
    const int sl = tid >> 4;

    for (int idx = c; idx < n; idx += 32) {
        const int b  = list[r * 4096 + idx];
        const int sv = selbuf[b];
        const int js = sv & 7, cs = sv >> 3;

        {
            const float4* h4 = reinterpret_cast<const float4*>(hidden);
            float4 v;
            if (tid < 128) v = h4[((size_t)b * 8 + js) * 128 + tid];
            else           v = h4[((size_t)b * 8 + cs) * 128 + (tid - 128)];
            *reinterpret_cast<float4*>(&comb[tid * 4]) = v;
        }
        __syncthreads();

        float a = 0.f;
        for (int i = 0; i < 64; ++i) {
            int rr = i * 16 + sl;
            a += comb[rr] * w1s[rr * 16 + e];
        }
        a += __shfl_xor(a, 16);
        a += __shfl_xor(a, 32);
        if ((sl & 3) == 0) part[sl >> 2][e] = a;
        __syncthreads();
        if (tid < 16)
            s_h1[tid] = fmaxf(part[0][tid] + part[1][tid] + part[2][tid] + part[3][tid], 0.f);
        __syncthreads();

        const float* w2 = W2 + (size_t)r * 8192;
        int o0 = tid * 2;
        float a0 = 0.f, a1 = 0.f;
        #pragma unroll
        for (int ee = 0; ee < 16; ++ee) {
            float h1e = s_h1[ee];
            float2 ww = *reinterpret_cast<const float2*>(w2 + ee * 512 + o0);
            a0 += h1e * ww.x;
            a1 += h1e * ww.y;
        }
        float2 nz = make_float2(a0, a1);
        float2 zz = make_float2(0.f, 0.f);
        float2* ob = reinterpret_cast<float2*>(outbuf + (size_t)b * 4096);
        #pragma unroll
        for (int v = 0; v < 8; ++v)
            ob[v * 256 + tid] = (v == js) ? nz : zz;
    }
}

extern "C" void kernel_launch(void* const* d_in, const int* in_sizes, int n_in,
                              void* d_out, int out_size, void* d_ws, size_t ws_size,
                              hipStream_t stream) {
    const float* hidden   = (const float*)d_in[0];
    const float* u_var    = (const float*)d_in[1];
    const float* u_rule   = (const float*)d_in[2];
    const float* Wq       = (const float*)d_in[3];
    const float* bq       = (const float*)d_in[4];
    const float* Wk       = (const float*)d_in[5];
    const float* bk       = (const float*)d_in[6];
    const float* rule_emb = (const float*)d_in[7];
    const float* Wq2      = (const float*)d_in[8];
    const float* bq2      = (const float*)d_in[9];
    const float* Wk2      = (const float*)d_in[10];
    const float* bk2      = (const float*)d_in[11];
    const float* W1       = (const float*)d_in[12];
    const float* W2       = (const float*)d_in[13];

    char* ws = (char*)d_ws;
    float* k2f  = (float*)(ws);              // 512 f32
    int*   cnt  = (int*)(ws + 2048);         // 16 i32
    int*   sel  = (int*)(ws + 4096);         // 4096 i32
    int*   list = (int*)(ws + 20480);        // 16*4096 i32
    float* outf = (float*)d_out;

    hipLaunchKernelGGL(k1_kernel, dim3(512), dim3(256), 0, stream,
                       hidden, u_var, Wq, bq, Wk, bk,
                       rule_emb, Wk2, bk2, k2f, cnt, sel, outf);
    hipLaunchKernelGGL(k2sel_kernel, dim3(512), dim3(256), 0, stream,
                       hidden, u_rule, Wq2, bq2, k2f, sel, outf, cnt, list);
    hipLaunchKernelGGL(k3_kernel, dim3(512), dim3(256), 0, stream,
                       hidden, W1, W2, sel, cnt, list, outf);
}